// Round 12
// baseline (1636.469 us; speedup 1.0000x reference)
//
#include <hip/hip_runtime.h>

#define BATCH   16
#define NPTS    4096
#define NPOINT  1024
#define NSAMPLE 32

typedef float v2f __attribute__((ext_vector_type(2)));

// ---------------------------------------------------------------------------
// Kernel 1: farthest point sampling (r11 version, 610us — latency-floor for
// this structure; parked). 256 thr / 4 waves / 16 pts per thread in regs.
// ---------------------------------------------------------------------------
__global__ __attribute__((amdgpu_waves_per_eu(1, 1))) __launch_bounds__(256)
void fps_kernel(const float* __restrict__ xyz, float* __restrict__ new_xyz)
{
#pragma clang fp contract(off)
    const int b    = blockIdx.x;
    const int t    = threadIdx.x;
    const int lane = t & 63;
    const int wv   = t >> 6;                               // 0..3
    const float* xb = xyz + (size_t)b * NPTS * 3;

    __shared__ float sxyz4[NPTS * 4];                      // 64 KB, float4 stride
    __shared__ __align__(16) unsigned long long sCand[2][4];

    v2f px2[8], py2[8], pz2[8], dist2[8];
#pragma unroll
    for (int j = 0; j < 16; ++j) {
        const int n = j * 256 + t;
        float X = xb[n * 3 + 0];
        float Y = xb[n * 3 + 1];
        float Z = xb[n * 3 + 2];
        sxyz4[n * 4 + 0] = X; sxyz4[n * 4 + 1] = Y; sxyz4[n * 4 + 2] = Z;
        asm volatile("" : "+v"(X), "+v"(Y), "+v"(Z));
        const int p = j >> 1;
        if (j & 1) { px2[p].y = X; py2[p].y = Y; pz2[p].y = Z; dist2[p].y = 1e10f; }
        else       { px2[p].x = X; py2[p].x = Y; pz2[p].x = Z; dist2[p].x = 1e10f; }
    }
    __syncthreads();

    float cx = sxyz4[0], cy = sxyz4[1], cz = sxyz4[2];     // first centroid = pt 0
    float* out = new_xyz + (size_t)b * NPOINT * 3;

    for (int i = 0; i < NPOINT; ++i) {
        if (t == 0) { out[i*3+0] = cx; out[i*3+1] = cy; out[i*3+2] = cz; }

        v2f c2x; c2x.x = cx; c2x.y = cx;
        v2f c2y; c2y.x = cy; c2y.y = cy;
        v2f c2z; c2z.x = cz; c2z.y = cz;
#pragma unroll
        for (int p = 0; p < 8; ++p) {
            v2f dx = px2[p] - c2x;
            v2f dy = py2[p] - c2y;
            v2f dz = pz2[p] - c2z;
            v2f xx = dx * dx;
            v2f yy = dy * dy;
            v2f zz = dz * dz;
            v2f ss = (xx + yy) + zz;
            dist2[p].x = fminf(dist2[p].x, ss.x);
            dist2[p].y = fminf(dist2[p].y, ss.y);
        }

#define D(j) ((j) & 1 ? dist2[(j) >> 1].y : dist2[(j) >> 1].x)
        float mA = fmaxf(fmaxf(D(0),  D(1)),  D(2));
        float mB = fmaxf(fmaxf(D(3),  D(4)),  D(5));
        float mC = fmaxf(fmaxf(D(6),  D(7)),  D(8));
        float mD = fmaxf(fmaxf(D(9),  D(10)), D(11));
        float mE = fmaxf(fmaxf(D(12), D(13)), D(14));
        float mx = fmaxf(fmaxf(fmaxf(mA, mB), mC),
                         fmaxf(fmaxf(mD, mE), D(15)));
        int bj = 15;
#pragma unroll
        for (int j = 15; j >= 0; --j) bj = (D(j) == mx) ? j : bj;
#undef D
        const int bidx = bj * 256 + t;

        unsigned long long cand =
            ((unsigned long long)__float_as_uint(mx) << 32) |
            (unsigned long long)(unsigned int)~bidx;

#define DPP_RED(CTRL, RMASK)                                                   \
        {                                                                      \
            unsigned int oh = (unsigned int)__builtin_amdgcn_update_dpp(       \
                0, (int)(unsigned int)(cand >> 32), (CTRL), (RMASK), 0xF, true);\
            unsigned int ol = (unsigned int)__builtin_amdgcn_update_dpp(       \
                0, (int)(unsigned int)cand, (CTRL), (RMASK), 0xF, true);       \
            unsigned long long o =                                             \
                ((unsigned long long)oh << 32) | (unsigned long long)ol;       \
            if (o > cand) cand = o;                                            \
        }
        DPP_RED(0x121, 0xF)
        DPP_RED(0x122, 0xF)
        DPP_RED(0x124, 0xF)
        DPP_RED(0x128, 0xF)
        DPP_RED(0x142, 0xA)
        DPP_RED(0x143, 0xC)
#undef DPP_RED

        const int par = i & 1;
        if (lane == 63) sCand[par][wv] = cand;
        __syncthreads();

        const ulonglong2* pc = (const ulonglong2*)&sCand[par][0];
        ulonglong2 r0 = pc[0], r1 = pc[1];
        const float4* sx4 = (const float4*)sxyz4;
        float4 f0 = sx4[~(unsigned int)r0.x];
        float4 f1 = sx4[~(unsigned int)r0.y];
        float4 f2 = sx4[~(unsigned int)r1.x];
        float4 f3 = sx4[~(unsigned int)r1.y];
        bool s01 = r0.y > r0.x;
        bool s23 = r1.y > r1.x;
        unsigned long long m01 = s01 ? r0.y : r0.x;
        unsigned long long m23 = s23 ? r1.y : r1.x;
        float4 g01; g01.x = s01 ? f1.x : f0.x; g01.y = s01 ? f1.y : f0.y; g01.z = s01 ? f1.z : f0.z;
        float4 g23; g23.x = s23 ? f3.x : f2.x; g23.y = s23 ? f3.y : f2.y; g23.z = s23 ? f3.z : f2.z;
        bool sF = m23 > m01;
        cx = sF ? g23.x : g01.x;
        cy = sF ? g23.y : g01.y;
        cz = sF ? g23.z : g01.z;
    }
}

// ---------------------------------------------------------------------------
// Kernel 2: ball query. VALIDATED — do not change arithmetic.
// ---------------------------------------------------------------------------
__global__ __launch_bounds__(256)
void ball_kernel(const float* __restrict__ xyz, const float* __restrict__ new_xyz,
                 int* __restrict__ idx)
{
    const int q    = blockIdx.x * 4 + (threadIdx.x >> 6);
    const int lane = threadIdx.x & 63;
    const int b    = q >> 10;
    const float* xb = xyz + (size_t)b * NPTS * 3;

    const float s0 = new_xyz[q*3+0];
    const float s1 = new_xyz[q*3+1];
    const float s2 = new_xyz[q*3+2];
    const float ssum = __fadd_rn(__fadd_rn(__fmul_rn(s0,s0), __fmul_rn(s1,s1)),
                                 __fmul_rn(s2,s2));
    const float r2 = (float)(0.2 * 0.2);

    int* myidx = idx + (size_t)q * NSAMPLE;
    int found = 0;
    int first = -1;

    for (int c = 0; c < NPTS / 64 && found < NSAMPLE; ++c) {
        int n = c * 64 + lane;
        float x = xb[n*3+0], y = xb[n*3+1], z = xb[n*3+2];
        float nsum = __fadd_rn(__fadd_rn(__fmul_rn(x,x), __fmul_rn(y,y)), __fmul_rn(z,z));
        float dot  = __fmaf_rn(s2, z, __fmaf_rn(s1, y, __fmul_rn(s0, x)));
        float d2   = __fsub_rn(__fadd_rn(ssum, nsum), __fmul_rn(2.0f, dot));
        bool inb = !(d2 > r2);
        unsigned long long m = __ballot(inb);
        if (first < 0 && m != 0ull) first = c * 64 + (int)__builtin_ctzll(m);
        if (inb) {
            int rank = __popcll(m & ((1ull << lane) - 1ull));
            int slot = found + rank;
            if (slot < NSAMPLE) myidx[slot] = n;
        }
        found += __popcll(m);
    }
    if (found > NSAMPLE) found = NSAMPLE;
    for (int slot = found + lane; slot < NSAMPLE; slot += 64) myidx[slot] = first;
}

// ---------------------------------------------------------------------------
// Kernel 3 (ROUND-12 REWRITE): gather + 3-layer MLP + max-pool with ZERO LDS
// weight traffic. Old structure re-read every weight from LDS per wave
// (3072 ds_read_b128/wave x 12cyc ~= 37k cyc > 25.6k VALU cyc => LDS-pipe
// bound). New: c-outer accumulation — acc[64] in registers, weight ROWS are
// contiguous and wave-uniform => global float4 broadcast reads (compiler
// scalarizes to s_load / L1-hit vmem; SMEM+vmem pipes hide under VALU).
// BN applied post-sum: y = acc*sc + (b - m*sc) — algebraically the same fold,
// continuous math (threshold has 10x headroom). LDS holds only folded
// scale/bias (1 KB). waves_per_eu(2,2): 256-VGPR cap fits x[64]+acc[64]+temps
// (~170) with 2 waves/SIMD for latency hiding.
// Lane = (s_local*32 + k), one sample per lane, pool = 5x shfl_xor.
// ---------------------------------------------------------------------------
__global__ __attribute__((amdgpu_waves_per_eu(2, 2))) __launch_bounds__(256)
void mlp_kernel(const float* __restrict__ xyz, const float* __restrict__ points,
                const float* __restrict__ new_xyz, const int* __restrict__ idx,
                const float* __restrict__ W1, const float* __restrict__ g1,
                const float* __restrict__ b1, const float* __restrict__ m1,
                const float* __restrict__ v1,
                const float* __restrict__ W2, const float* __restrict__ g2,
                const float* __restrict__ b2, const float* __restrict__ m2,
                const float* __restrict__ v2,
                const float* __restrict__ W3, const float* __restrict__ g3,
                const float* __restrict__ b3, const float* __restrict__ m3,
                const float* __restrict__ v3,
                float* __restrict__ feat)
{
    __shared__ float sc1[64], bi1[64], sc2[64], bi2[64], sc3[128], bi3[128];

    const int tid = threadIdx.x;
    for (int d = tid; d < 64; d += 256) {
        float s1v = g1[d] / sqrtf(v1[d] + 1e-5f);
        sc1[d] = s1v; bi1[d] = b1[d] - m1[d] * s1v;
        float s2v = g2[d] / sqrtf(v2[d] + 1e-5f);
        sc2[d] = s2v; bi2[d] = b2[d] - m2[d] * s2v;
    }
    for (int d = tid; d < 128; d += 256) {
        float s3v = g3[d] / sqrtf(v3[d] + 1e-5f);
        sc3[d] = s3v; bi3[d] = b3[d] - m3[d] * s3v;
    }
    __syncthreads();

    const int wid  = tid >> 6;
    const int lane = tid & 63;
    const int q = blockIdx.x * 8 + wid * 2 + (lane >> 5);
    const int k = lane & 31;
    const int b = q >> 10;

    const int n = idx[(size_t)q * NSAMPLE + k];
    const float* xp = xyz    + ((size_t)b * NPTS + n) * 3;
    const float* pp = points + ((size_t)b * NPTS + n) * 3;
    const float* nx = new_xyz + (size_t)q * 3;

    float in[6];
    in[0] = __fsub_rn(xp[0], nx[0]);
    in[1] = __fsub_rn(xp[1], nx[1]);
    in[2] = __fsub_rn(xp[2], nx[2]);
    in[3] = pp[0]; in[4] = pp[1]; in[5] = pp[2];

    float x[64];
    float acc[64];

    // ---- Layer 1: 6 -> 64, c-outer, wave-uniform weight rows ----
#pragma unroll
    for (int d = 0; d < 64; ++d) acc[d] = 0.f;
#pragma unroll
    for (int c = 0; c < 6; ++c) {
        const float4* wr = (const float4*)(W1 + c * 64);
        const float xc = in[c];
#pragma unroll
        for (int dd = 0; dd < 16; ++dd) {
            float4 w = wr[dd];
            acc[4*dd+0] = fmaf(xc, w.x, acc[4*dd+0]);
            acc[4*dd+1] = fmaf(xc, w.y, acc[4*dd+1]);
            acc[4*dd+2] = fmaf(xc, w.z, acc[4*dd+2]);
            acc[4*dd+3] = fmaf(xc, w.w, acc[4*dd+3]);
        }
    }
#pragma unroll
    for (int d = 0; d < 64; ++d)
        x[d] = fmaxf(fmaf(acc[d], sc1[d], bi1[d]), 0.f);

    // ---- Layer 2: 64 -> 64 ----
#pragma unroll
    for (int d = 0; d < 64; ++d) acc[d] = 0.f;
#pragma unroll
    for (int c = 0; c < 64; ++c) {
        const float4* wr = (const float4*)(W2 + c * 64);
        const float xc = x[c];
#pragma unroll
        for (int dd = 0; dd < 16; ++dd) {
            float4 w = wr[dd];
            acc[4*dd+0] = fmaf(xc, w.x, acc[4*dd+0]);
            acc[4*dd+1] = fmaf(xc, w.y, acc[4*dd+1]);
            acc[4*dd+2] = fmaf(xc, w.z, acc[4*dd+2]);
            acc[4*dd+3] = fmaf(xc, w.w, acc[4*dd+3]);
        }
    }
#pragma unroll
    for (int d = 0; d < 64; ++d)
        x[d] = fmaxf(fmaf(acc[d], sc2[d], bi2[d]), 0.f);

    // ---- Layer 3: 64 -> 128 in two halves of 64; fused pool + store ----
    float* fq = feat + (size_t)q * 128;
#pragma unroll
    for (int half = 0; half < 2; ++half) {
#pragma unroll
        for (int d = 0; d < 64; ++d) acc[d] = 0.f;
#pragma unroll
        for (int c = 0; c < 64; ++c) {
            const float4* wr = (const float4*)(W3 + c * 128 + half * 64);
            const float xc = x[c];
#pragma unroll
            for (int dd = 0; dd < 16; ++dd) {
                float4 w = wr[dd];
                acc[4*dd+0] = fmaf(xc, w.x, acc[4*dd+0]);
                acc[4*dd+1] = fmaf(xc, w.y, acc[4*dd+1]);
                acc[4*dd+2] = fmaf(xc, w.z, acc[4*dd+2]);
                acc[4*dd+3] = fmaf(xc, w.w, acc[4*dd+3]);
            }
        }
        // epilogue + max-pool over the 32 k-lanes + float4 stores
#pragma unroll
        for (int dg = 0; dg < 16; ++dg) {
            float st[4];
#pragma unroll
            for (int j = 0; j < 4; ++j) {
                const int d = dg * 4 + j;
                const int dc = half * 64 + d;
                float vv = fmaxf(fmaf(acc[d], sc3[dc], bi3[dc]), 0.f);
#pragma unroll
                for (int off = 16; off >= 1; off >>= 1)
                    vv = fmaxf(vv, __shfl_xor(vv, off));
                st[j] = vv;
            }
            if (k == 0) {
                float4 v4; v4.x = st[0]; v4.y = st[1]; v4.z = st[2]; v4.w = st[3];
                *(float4*)&fq[half * 64 + dg * 4] = v4;
            }
        }
    }
}

extern "C" void kernel_launch(void* const* d_in, const int* in_sizes, int n_in,
                              void* d_out, int out_size, void* d_ws, size_t ws_size,
                              hipStream_t stream)
{
    (void)in_sizes; (void)n_in; (void)out_size; (void)ws_size;

    const float* xyz    = (const float*)d_in[0];
    const float* points = (const float*)d_in[1];
    const float* W1 = (const float*)d_in[2];
    const float* g1 = (const float*)d_in[3];
    const float* b1 = (const float*)d_in[4];
    const float* m1 = (const float*)d_in[5];
    const float* v1 = (const float*)d_in[6];
    const float* W2 = (const float*)d_in[7];
    const float* g2 = (const float*)d_in[8];
    const float* b2 = (const float*)d_in[9];
    const float* m2 = (const float*)d_in[10];
    const float* v2 = (const float*)d_in[11];
    const float* W3 = (const float*)d_in[12];
    const float* g3 = (const float*)d_in[13];
    const float* b3 = (const float*)d_in[14];
    const float* m3 = (const float*)d_in[15];
    const float* v3 = (const float*)d_in[16];

    float* out_f    = (float*)d_out;
    float* new_xyz  = out_f;                                  // B*NPOINT*3
    float* feat     = out_f + (size_t)BATCH * NPOINT * 3;     // B*NPOINT*128
    int*   idx      = (int*)d_ws;                             // B*NPOINT*NSAMPLE ints

    fps_kernel <<<BATCH, 256, 0, stream>>>(xyz, new_xyz);
    ball_kernel<<<(BATCH * NPOINT) / 4, 256, 0, stream>>>(xyz, new_xyz, idx);
    mlp_kernel <<<(BATCH * NPOINT) / 8, 256, 0, stream>>>(xyz, points, new_xyz, idx,
        W1, g1, b1, m1, v1, W2, g2, b2, m2, v2, W3, g3, b3, m3, v3, feat);
}

// Round 13
// 921.594 us; speedup vs baseline: 1.7757x; 1.7757x over previous
//
#include <hip/hip_runtime.h>

#define BATCH   16
#define NPTS    4096
#define NPOINT  1024
#define NSAMPLE 32

typedef float v2f __attribute__((ext_vector_type(2)));

// ---------------------------------------------------------------------------
// Kernel 1: farthest point sampling. 256 thr / 4 waves / 16 pts per thread in
// regs (VGPR=132 resident, r10-verified).
// ROUND-13: RAW barrier. __syncthreads always compiles to
// `s_waitcnt vmcnt(0) lgkmcnt(0); s_barrier`, so wave 0's per-iteration
// global store of the centroid stalls ALL waves on store retirement
// (~200-300cyc) every iteration (r9 LDS-staging didn't test this — the
// compiler drains vmcnt at the barrier regardless). The raw
// `s_waitcnt lgkmcnt(0); s_barrier` preserves all LDS ordering (ds ops are
// lgkmcnt-tracked; consumers are ds_reads ordered by the memory clobber) but
// lets the stores retire asynchronously. Stores go to distinct addresses,
// read only after kernel end (dispatch-end drain guarantees visibility).
// ---------------------------------------------------------------------------
__global__ __attribute__((amdgpu_waves_per_eu(1, 1))) __launch_bounds__(256)
void fps_kernel(const float* __restrict__ xyz, float* __restrict__ new_xyz)
{
#pragma clang fp contract(off)
    const int b    = blockIdx.x;
    const int t    = threadIdx.x;
    const int lane = t & 63;
    const int wv   = t >> 6;                               // 0..3
    const float* xb = xyz + (size_t)b * NPTS * 3;

    __shared__ float sxyz4[NPTS * 4];                      // 64 KB, float4 stride
    __shared__ __align__(16) unsigned long long sCand[2][4];

    v2f px2[8], py2[8], pz2[8], dist2[8];
#pragma unroll
    for (int j = 0; j < 16; ++j) {
        const int n = j * 256 + t;
        float X = xb[n * 3 + 0];
        float Y = xb[n * 3 + 1];
        float Z = xb[n * 3 + 2];
        sxyz4[n * 4 + 0] = X; sxyz4[n * 4 + 1] = Y; sxyz4[n * 4 + 2] = Z;
        asm volatile("" : "+v"(X), "+v"(Y), "+v"(Z));
        const int p = j >> 1;
        if (j & 1) { px2[p].y = X; py2[p].y = Y; pz2[p].y = Z; dist2[p].y = 1e10f; }
        else       { px2[p].x = X; py2[p].x = Y; pz2[p].x = Z; dist2[p].x = 1e10f; }
    }
    __syncthreads();

    float cx = sxyz4[0], cy = sxyz4[1], cz = sxyz4[2];     // first centroid = pt 0
    float* out = new_xyz + (size_t)b * NPOINT * 3;

    for (int i = 0; i < NPOINT; ++i) {
        if (t == 0) { out[i*3+0] = cx; out[i*3+1] = cy; out[i*3+2] = cz; }

        v2f c2x; c2x.x = cx; c2x.y = cx;
        v2f c2y; c2y.x = cy; c2y.y = cy;
        v2f c2z; c2z.x = cz; c2z.y = cz;
#pragma unroll
        for (int p = 0; p < 8; ++p) {
            v2f dx = px2[p] - c2x;
            v2f dy = py2[p] - c2y;
            v2f dz = pz2[p] - c2z;
            v2f xx = dx * dx;
            v2f yy = dy * dy;
            v2f zz = dz * dz;
            v2f ss = (xx + yy) + zz;
            dist2[p].x = fminf(dist2[p].x, ss.x);
            dist2[p].y = fminf(dist2[p].y, ss.y);
        }

#define D(j) ((j) & 1 ? dist2[(j) >> 1].y : dist2[(j) >> 1].x)
        float mA = fmaxf(fmaxf(D(0),  D(1)),  D(2));
        float mB = fmaxf(fmaxf(D(3),  D(4)),  D(5));
        float mC = fmaxf(fmaxf(D(6),  D(7)),  D(8));
        float mD = fmaxf(fmaxf(D(9),  D(10)), D(11));
        float mE = fmaxf(fmaxf(D(12), D(13)), D(14));
        float mx = fmaxf(fmaxf(fmaxf(mA, mB), mC),
                         fmaxf(fmaxf(mD, mE), D(15)));
        int bj = 15;
#pragma unroll
        for (int j = 15; j >= 0; --j) bj = (D(j) == mx) ? j : bj;
#undef D
        const int bidx = bj * 256 + t;

        unsigned long long cand =
            ((unsigned long long)__float_as_uint(mx) << 32) |
            (unsigned long long)(unsigned int)~bidx;

#define DPP_RED(CTRL, RMASK)                                                   \
        {                                                                      \
            unsigned int oh = (unsigned int)__builtin_amdgcn_update_dpp(       \
                0, (int)(unsigned int)(cand >> 32), (CTRL), (RMASK), 0xF, true);\
            unsigned int ol = (unsigned int)__builtin_amdgcn_update_dpp(       \
                0, (int)(unsigned int)cand, (CTRL), (RMASK), 0xF, true);       \
            unsigned long long o =                                             \
                ((unsigned long long)oh << 32) | (unsigned long long)ol;       \
            if (o > cand) cand = o;                                            \
        }
        DPP_RED(0x121, 0xF)
        DPP_RED(0x122, 0xF)
        DPP_RED(0x124, 0xF)
        DPP_RED(0x128, 0xF)
        DPP_RED(0x142, 0xA)
        DPP_RED(0x143, 0xC)
#undef DPP_RED

        const int par = i & 1;
        if (lane == 63) sCand[par][wv] = cand;
        // RAW barrier: drain LDS only (lgkmcnt), NOT the in-flight global
        // stores (vmcnt) — that drain was stalling all waves each iteration.
        asm volatile("s_waitcnt lgkmcnt(0)\n\ts_barrier" ::: "memory");

        const ulonglong2* pc = (const ulonglong2*)&sCand[par][0];
        ulonglong2 r0 = pc[0], r1 = pc[1];
        const float4* sx4 = (const float4*)sxyz4;
        float4 f0 = sx4[~(unsigned int)r0.x];
        float4 f1 = sx4[~(unsigned int)r0.y];
        float4 f2 = sx4[~(unsigned int)r1.x];
        float4 f3 = sx4[~(unsigned int)r1.y];
        bool s01 = r0.y > r0.x;
        bool s23 = r1.y > r1.x;
        unsigned long long m01 = s01 ? r0.y : r0.x;
        unsigned long long m23 = s23 ? r1.y : r1.x;
        float4 g01; g01.x = s01 ? f1.x : f0.x; g01.y = s01 ? f1.y : f0.y; g01.z = s01 ? f1.z : f0.z;
        float4 g23; g23.x = s23 ? f3.x : f2.x; g23.y = s23 ? f3.y : f2.y; g23.z = s23 ? f3.z : f2.z;
        bool sF = m23 > m01;
        cx = sF ? g23.x : g01.x;
        cy = sF ? g23.y : g01.y;
        cz = sF ? g23.z : g01.z;
    }
}

// ---------------------------------------------------------------------------
// Kernel 2: ball query. VALIDATED — do not change arithmetic.
// ---------------------------------------------------------------------------
__global__ __launch_bounds__(256)
void ball_kernel(const float* __restrict__ xyz, const float* __restrict__ new_xyz,
                 int* __restrict__ idx)
{
    const int q    = blockIdx.x * 4 + (threadIdx.x >> 6);
    const int lane = threadIdx.x & 63;
    const int b    = q >> 10;
    const float* xb = xyz + (size_t)b * NPTS * 3;

    const float s0 = new_xyz[q*3+0];
    const float s1 = new_xyz[q*3+1];
    const float s2 = new_xyz[q*3+2];
    const float ssum = __fadd_rn(__fadd_rn(__fmul_rn(s0,s0), __fmul_rn(s1,s1)),
                                 __fmul_rn(s2,s2));
    const float r2 = (float)(0.2 * 0.2);

    int* myidx = idx + (size_t)q * NSAMPLE;
    int found = 0;
    int first = -1;

    for (int c = 0; c < NPTS / 64 && found < NSAMPLE; ++c) {
        int n = c * 64 + lane;
        float x = xb[n*3+0], y = xb[n*3+1], z = xb[n*3+2];
        float nsum = __fadd_rn(__fadd_rn(__fmul_rn(x,x), __fmul_rn(y,y)), __fmul_rn(z,z));
        float dot  = __fmaf_rn(s2, z, __fmaf_rn(s1, y, __fmul_rn(s0, x)));
        float d2   = __fsub_rn(__fadd_rn(ssum, nsum), __fmul_rn(2.0f, dot));
        bool inb = !(d2 > r2);
        unsigned long long m = __ballot(inb);
        if (first < 0 && m != 0ull) first = c * 64 + (int)__builtin_ctzll(m);
        if (inb) {
            int rank = __popcll(m & ((1ull << lane) - 1ull));
            int slot = found + rank;
            if (slot < NSAMPLE) myidx[slot] = n;
        }
        found += __popcll(m);
    }
    if (found > NSAMPLE) found = NSAMPLE;
    for (int slot = found + lane; slot < NSAMPLE; slot += 64) myidx[slot] = first;
}

// ---------------------------------------------------------------------------
// Kernel 3: gather + 3-layer MLP + max-pool — REVERTED to the r11 LDS-
// broadcast structure (r12 c-outer rewrite spilled: VGPR=104 + 18MB scratch
// writes, 5x slower). Change vs r11: inner products pair the c dimension as
// v2f and use v_pk_fma_f32 (halves VALU issue); x lives as v2f[32] so the
// register footprint is unchanged. Reassociation (even/odd partial sums) is
// continuous math — 10x threshold headroom.
// ---------------------------------------------------------------------------
__global__ __launch_bounds__(256)
void mlp_kernel(const float* __restrict__ xyz, const float* __restrict__ points,
                const float* __restrict__ new_xyz, const int* __restrict__ idx,
                const float* __restrict__ W1, const float* __restrict__ g1,
                const float* __restrict__ b1, const float* __restrict__ m1,
                const float* __restrict__ v1,
                const float* __restrict__ W2, const float* __restrict__ g2,
                const float* __restrict__ b2, const float* __restrict__ m2,
                const float* __restrict__ v2,
                const float* __restrict__ W3, const float* __restrict__ g3,
                const float* __restrict__ b3, const float* __restrict__ m3,
                const float* __restrict__ v3,
                float* __restrict__ feat)
{
    __shared__ float w1t[64][8];     // [out][in(6, padded 8)]
    __shared__ float w2t[64][64];    // [out][in]
    __shared__ float w3t[128][64];   // [out][in]
    __shared__ float bias1s[64], bias2s[64], bias3s[128];
    __shared__ float sc1[64], sc2[64], sc3[128];

    const int tid = threadIdx.x;

    for (int d = tid; d < 64; d += 256) {
        float s1v = g1[d] / sqrtf(v1[d] + 1e-5f);
        sc1[d] = s1v; bias1s[d] = b1[d] - m1[d] * s1v;
        float s2v = g2[d] / sqrtf(v2[d] + 1e-5f);
        sc2[d] = s2v; bias2s[d] = b2[d] - m2[d] * s2v;
    }
    for (int d = tid; d < 128; d += 256) {
        float s3v = g3[d] / sqrtf(v3[d] + 1e-5f);
        sc3[d] = s3v; bias3s[d] = b3[d] - m3[d] * s3v;
    }
    __syncthreads();
    for (int e = tid; e < 64 * 8; e += 256) {
        int d = e >> 3, c = e & 7;
        w1t[d][c] = (c < 6) ? W1[c * 64 + d] * sc1[d] : 0.f;
    }
    for (int e = tid; e < 64 * 64; e += 256) {
        int d = e >> 6, c = e & 63;
        w2t[d][c] = W2[c * 64 + d] * sc2[d];
    }
    for (int e = tid; e < 128 * 64; e += 256) {
        int d = e >> 6, c = e & 63;
        w3t[d][c] = W3[c * 128 + d] * sc3[d];
    }
    __syncthreads();

    const int wid  = tid >> 6;
    const int lane = tid & 63;
    const int q = blockIdx.x * 8 + wid * 2 + (lane >> 5);
    const int k = lane & 31;
    const int b = q >> 10;

    const int n = idx[(size_t)q * NSAMPLE + k];
    const float* xp = xyz    + ((size_t)b * NPTS + n) * 3;
    const float* pp = points + ((size_t)b * NPTS + n) * 3;
    const float* nx = new_xyz + (size_t)q * 3;

    const float in0 = __fsub_rn(xp[0], nx[0]);
    const float in1 = __fsub_rn(xp[1], nx[1]);
    const float in2 = __fsub_rn(xp[2], nx[2]);
    const float in3 = pp[0], in4 = pp[1], in5 = pp[2];

    // ---- Layer 1: 6 -> 64 (scalar; tiny) -> x2 as v2f[32] ----
    v2f x2[32];
#pragma unroll
    for (int d = 0; d < 64; ++d) {
        const float4 wa = *(const float4*)&w1t[d][0];
        const float4 wb = *(const float4*)&w1t[d][4];
        float acc = bias1s[d];
        acc = fmaf(in0, wa.x, acc);
        acc = fmaf(in1, wa.y, acc);
        acc = fmaf(in2, wa.z, acc);
        acc = fmaf(in3, wa.w, acc);
        acc = fmaf(in4, wb.x, acc);
        acc = fmaf(in5, wb.y, acc);
        float r = fmaxf(acc, 0.f);
        if (d & 1) x2[d >> 1].y = r; else x2[d >> 1].x = r;
    }

    // ---- Layer 2: 64 -> 64, v_pk_fma over c-pairs ----
    v2f y2[32];
#pragma unroll
    for (int d = 0; d < 64; ++d) {
        v2f a2; a2.x = 0.f; a2.y = 0.f;
        const float4* wr = (const float4*)w2t[d];
#pragma unroll
        for (int cc = 0; cc < 16; ++cc) {
            float4 w = wr[cc];
            v2f wlo; wlo.x = w.x; wlo.y = w.y;
            v2f whi; whi.x = w.z; whi.y = w.w;
            a2 += x2[2*cc]     * wlo;
            a2 += x2[2*cc + 1] * whi;
        }
        float r = fmaxf(bias2s[d] + (a2.x + a2.y), 0.f);
        if (d & 1) y2[d >> 1].y = r; else y2[d >> 1].x = r;
    }

    // ---- Layer 3: 64 -> 128, v_pk_fma, fused max-pool + store ----
    float* fq = feat + (size_t)q * 128;
#pragma unroll
    for (int d = 0; d < 128; ++d) {
        v2f a2; a2.x = 0.f; a2.y = 0.f;
        const float4* wr = (const float4*)w3t[d];
#pragma unroll
        for (int cc = 0; cc < 16; ++cc) {
            float4 w = wr[cc];
            v2f wlo; wlo.x = w.x; wlo.y = w.y;
            v2f whi; whi.x = w.z; whi.y = w.w;
            a2 += y2[2*cc]     * wlo;
            a2 += y2[2*cc + 1] * whi;
        }
        float vv = fmaxf(bias3s[d] + (a2.x + a2.y), 0.f);
#pragma unroll
        for (int off = 16; off >= 1; off >>= 1)
            vv = fmaxf(vv, __shfl_xor(vv, off));
        if (k == 0) fq[d] = vv;
    }
}

extern "C" void kernel_launch(void* const* d_in, const int* in_sizes, int n_in,
                              void* d_out, int out_size, void* d_ws, size_t ws_size,
                              hipStream_t stream)
{
    (void)in_sizes; (void)n_in; (void)out_size; (void)ws_size;

    const float* xyz    = (const float*)d_in[0];
    const float* points = (const float*)d_in[1];
    const float* W1 = (const float*)d_in[2];
    const float* g1 = (const float*)d_in[3];
    const float* b1 = (const float*)d_in[4];
    const float* m1 = (const float*)d_in[5];
    const float* v1 = (const float*)d_in[6];
    const float* W2 = (const float*)d_in[7];
    const float* g2 = (const float*)d_in[8];
    const float* b2 = (const float*)d_in[9];
    const float* m2 = (const float*)d_in[10];
    const float* v2 = (const float*)d_in[11];
    const float* W3 = (const float*)d_in[12];
    const float* g3 = (const float*)d_in[13];
    const float* b3 = (const float*)d_in[14];
    const float* m3 = (const float*)d_in[15];
    const float* v3 = (const float*)d_in[16];

    float* out_f    = (float*)d_out;
    float* new_xyz  = out_f;                                  // B*NPOINT*3
    float* feat     = out_f + (size_t)BATCH * NPOINT * 3;     // B*NPOINT*128
    int*   idx      = (int*)d_ws;                             // B*NPOINT*NSAMPLE ints

    fps_kernel <<<BATCH, 256, 0, stream>>>(xyz, new_xyz);
    ball_kernel<<<(BATCH * NPOINT) / 4, 256, 0, stream>>>(xyz, new_xyz, idx);
    mlp_kernel <<<(BATCH * NPOINT) / 8, 256, 0, stream>>>(xyz, points, new_xyz, idx,
        W1, g1, b1, m1, v1, W2, g2, b2, m2, v2, W3, g3, b3, m3, v3, feat);
}

// Round 14
// 904.872 us; speedup vs baseline: 1.8085x; 1.0185x over previous
//
#include <hip/hip_runtime.h>

#define BATCH   16
#define NPTS    4096
#define NPOINT  1024
#define NSAMPLE 32

typedef float v2f __attribute__((ext_vector_type(2)));

// ---------------------------------------------------------------------------
// Kernel 1: farthest point sampling (parked at ~608us: six structural
// variants r5-r13 all land at 586-630 ns/iter -> serial barrier+LDS floor).
// 256 thr / 4 waves / 16 pts per thread in regs (VGPR=132, resident).
// ---------------------------------------------------------------------------
__global__ __attribute__((amdgpu_waves_per_eu(1, 1))) __launch_bounds__(256)
void fps_kernel(const float* __restrict__ xyz, float* __restrict__ new_xyz)
{
#pragma clang fp contract(off)
    const int b    = blockIdx.x;
    const int t    = threadIdx.x;
    const int lane = t & 63;
    const int wv   = t >> 6;                               // 0..3
    const float* xb = xyz + (size_t)b * NPTS * 3;

    __shared__ float sxyz4[NPTS * 4];                      // 64 KB, float4 stride
    __shared__ __align__(16) unsigned long long sCand[2][4];

    v2f px2[8], py2[8], pz2[8], dist2[8];
#pragma unroll
    for (int j = 0; j < 16; ++j) {
        const int n = j * 256 + t;
        float X = xb[n * 3 + 0];
        float Y = xb[n * 3 + 1];
        float Z = xb[n * 3 + 2];
        sxyz4[n * 4 + 0] = X; sxyz4[n * 4 + 1] = Y; sxyz4[n * 4 + 2] = Z;
        asm volatile("" : "+v"(X), "+v"(Y), "+v"(Z));
        const int p = j >> 1;
        if (j & 1) { px2[p].y = X; py2[p].y = Y; pz2[p].y = Z; dist2[p].y = 1e10f; }
        else       { px2[p].x = X; py2[p].x = Y; pz2[p].x = Z; dist2[p].x = 1e10f; }
    }
    __syncthreads();

    float cx = sxyz4[0], cy = sxyz4[1], cz = sxyz4[2];     // first centroid = pt 0
    float* out = new_xyz + (size_t)b * NPOINT * 3;

    for (int i = 0; i < NPOINT; ++i) {
        if (t == 0) { out[i*3+0] = cx; out[i*3+1] = cy; out[i*3+2] = cz; }

        v2f c2x; c2x.x = cx; c2x.y = cx;
        v2f c2y; c2y.x = cy; c2y.y = cy;
        v2f c2z; c2z.x = cz; c2z.y = cz;
#pragma unroll
        for (int p = 0; p < 8; ++p) {
            v2f dx = px2[p] - c2x;
            v2f dy = py2[p] - c2y;
            v2f dz = pz2[p] - c2z;
            v2f xx = dx * dx;
            v2f yy = dy * dy;
            v2f zz = dz * dz;
            v2f ss = (xx + yy) + zz;
            dist2[p].x = fminf(dist2[p].x, ss.x);
            dist2[p].y = fminf(dist2[p].y, ss.y);
        }

#define D(j) ((j) & 1 ? dist2[(j) >> 1].y : dist2[(j) >> 1].x)
        float mA = fmaxf(fmaxf(D(0),  D(1)),  D(2));
        float mB = fmaxf(fmaxf(D(3),  D(4)),  D(5));
        float mC = fmaxf(fmaxf(D(6),  D(7)),  D(8));
        float mD = fmaxf(fmaxf(D(9),  D(10)), D(11));
        float mE = fmaxf(fmaxf(D(12), D(13)), D(14));
        float mx = fmaxf(fmaxf(fmaxf(mA, mB), mC),
                         fmaxf(fmaxf(mD, mE), D(15)));
        int bj = 15;
#pragma unroll
        for (int j = 15; j >= 0; --j) bj = (D(j) == mx) ? j : bj;
#undef D
        const int bidx = bj * 256 + t;

        unsigned long long cand =
            ((unsigned long long)__float_as_uint(mx) << 32) |
            (unsigned long long)(unsigned int)~bidx;

#define DPP_RED(CTRL, RMASK)                                                   \
        {                                                                      \
            unsigned int oh = (unsigned int)__builtin_amdgcn_update_dpp(       \
                0, (int)(unsigned int)(cand >> 32), (CTRL), (RMASK), 0xF, true);\
            unsigned int ol = (unsigned int)__builtin_amdgcn_update_dpp(       \
                0, (int)(unsigned int)cand, (CTRL), (RMASK), 0xF, true);       \
            unsigned long long o =                                             \
                ((unsigned long long)oh << 32) | (unsigned long long)ol;       \
            if (o > cand) cand = o;                                            \
        }
        DPP_RED(0x121, 0xF)
        DPP_RED(0x122, 0xF)
        DPP_RED(0x124, 0xF)
        DPP_RED(0x128, 0xF)
        DPP_RED(0x142, 0xA)
        DPP_RED(0x143, 0xC)
#undef DPP_RED

        const int par = i & 1;
        if (lane == 63) sCand[par][wv] = cand;
        asm volatile("s_waitcnt lgkmcnt(0)\n\ts_barrier" ::: "memory");

        const ulonglong2* pc = (const ulonglong2*)&sCand[par][0];
        ulonglong2 r0 = pc[0], r1 = pc[1];
        const float4* sx4 = (const float4*)sxyz4;
        float4 f0 = sx4[~(unsigned int)r0.x];
        float4 f1 = sx4[~(unsigned int)r0.y];
        float4 f2 = sx4[~(unsigned int)r1.x];
        float4 f3 = sx4[~(unsigned int)r1.y];
        bool s01 = r0.y > r0.x;
        bool s23 = r1.y > r1.x;
        unsigned long long m01 = s01 ? r0.y : r0.x;
        unsigned long long m23 = s23 ? r1.y : r1.x;
        float4 g01; g01.x = s01 ? f1.x : f0.x; g01.y = s01 ? f1.y : f0.y; g01.z = s01 ? f1.z : f0.z;
        float4 g23; g23.x = s23 ? f3.x : f2.x; g23.y = s23 ? f3.y : f2.y; g23.z = s23 ? f3.z : f2.z;
        bool sF = m23 > m01;
        cx = sF ? g23.x : g01.x;
        cy = sF ? g23.y : g01.y;
        cz = sF ? g23.z : g01.z;
    }
}

// ---------------------------------------------------------------------------
// Kernel 2: ball query. VALIDATED — do not change arithmetic.
// ---------------------------------------------------------------------------
__global__ __launch_bounds__(256)
void ball_kernel(const float* __restrict__ xyz, const float* __restrict__ new_xyz,
                 int* __restrict__ idx)
{
    const int q    = blockIdx.x * 4 + (threadIdx.x >> 6);
    const int lane = threadIdx.x & 63;
    const int b    = q >> 10;
    const float* xb = xyz + (size_t)b * NPTS * 3;

    const float s0 = new_xyz[q*3+0];
    const float s1 = new_xyz[q*3+1];
    const float s2 = new_xyz[q*3+2];
    const float ssum = __fadd_rn(__fadd_rn(__fmul_rn(s0,s0), __fmul_rn(s1,s1)),
                                 __fmul_rn(s2,s2));
    const float r2 = (float)(0.2 * 0.2);

    int* myidx = idx + (size_t)q * NSAMPLE;
    int found = 0;
    int first = -1;

    for (int c = 0; c < NPTS / 64 && found < NSAMPLE; ++c) {
        int n = c * 64 + lane;
        float x = xb[n*3+0], y = xb[n*3+1], z = xb[n*3+2];
        float nsum = __fadd_rn(__fadd_rn(__fmul_rn(x,x), __fmul_rn(y,y)), __fmul_rn(z,z));
        float dot  = __fmaf_rn(s2, z, __fmaf_rn(s1, y, __fmul_rn(s0, x)));
        float d2   = __fsub_rn(__fadd_rn(ssum, nsum), __fmul_rn(2.0f, dot));
        bool inb = !(d2 > r2);
        unsigned long long m = __ballot(inb);
        if (first < 0 && m != 0ull) first = c * 64 + (int)__builtin_ctzll(m);
        if (inb) {
            int rank = __popcll(m & ((1ull << lane) - 1ull));
            int slot = found + rank;
            if (slot < NSAMPLE) myidx[slot] = n;
        }
        found += __popcll(m);
    }
    if (found > NSAMPLE) found = NSAMPLE;
    for (int slot = found + lane; slot < NSAMPLE; slot += 64) myidx[slot] = first;
}

// ---------------------------------------------------------------------------
// Kernel P (ROUND-14): one-block prep — fold BN scale into TRANSPOSED weight
// copies in d_ws so mlp can read weight rows as contiguous, lane-invariant
// float4s (scalarizable to s_load / L1-broadcast). Layout in ws after the
// 2MB idx region: Wt1[64][8](pad) | Wt2[64][64] | Wt3[128][64] |
// bi1[64] | bi2[64] | bi3[128].
// ---------------------------------------------------------------------------
__global__ __launch_bounds__(256)
void prep_kernel(const float* __restrict__ W1, const float* __restrict__ g1,
                 const float* __restrict__ b1, const float* __restrict__ m1,
                 const float* __restrict__ v1,
                 const float* __restrict__ W2, const float* __restrict__ g2,
                 const float* __restrict__ b2, const float* __restrict__ m2,
                 const float* __restrict__ v2,
                 const float* __restrict__ W3, const float* __restrict__ g3,
                 const float* __restrict__ b3, const float* __restrict__ m3,
                 const float* __restrict__ v3,
                 float* __restrict__ wt)
{
    const int t = threadIdx.x;
    float* Wt1 = wt;                    // 512
    float* Wt2 = wt + 512;              // 4096
    float* Wt3 = wt + 512 + 4096;       // 8192
    float* bi1 = wt + 512 + 4096 + 8192;        // 64
    float* bi2 = bi1 + 64;                       // 64
    float* bi3 = bi2 + 64;                       // 128

    for (int e = t; e < 64 * 8; e += 256) {
        int d = e >> 3, c = e & 7;
        float sc = g1[d] / sqrtf(v1[d] + 1e-5f);
        Wt1[e] = (c < 6) ? W1[c * 64 + d] * sc : 0.f;
    }
    for (int e = t; e < 64 * 64; e += 256) {
        int d = e >> 6, c = e & 63;
        float sc = g2[d] / sqrtf(v2[d] + 1e-5f);
        Wt2[e] = W2[c * 64 + d] * sc;
    }
    for (int e = t; e < 128 * 64; e += 256) {
        int d = e >> 6, c = e & 63;
        float sc = g3[d] / sqrtf(v3[d] + 1e-5f);
        Wt3[e] = W3[c * 128 + d] * sc;
    }
    for (int d = t; d < 64; d += 256) {
        float s1v = g1[d] / sqrtf(v1[d] + 1e-5f);
        bi1[d] = b1[d] - m1[d] * s1v;
        float s2v = g2[d] / sqrtf(v2[d] + 1e-5f);
        bi2[d] = b2[d] - m2[d] * s2v;
    }
    for (int d = t; d < 128; d += 256) {
        float s3v = g3[d] / sqrtf(v3[d] + 1e-5f);
        bi3[d] = b3[d] - m3[d] * s3v;
    }
}

// ---------------------------------------------------------------------------
// Kernel 3 (ROUND-14): gather + 3-layer MLP + max-pool, ZERO LDS. Weights
// come from the prep kernel's folded+transposed global copies at
// lane-invariant addresses (scalar path / L1 broadcast) — removes the LDS
// pipe bottleneck (r13 model: ~3200 ds_read_b128 per wave through 1 pipe,
// shared by 12 waves/CU). Numerics identical to validated r13 (same fold,
// same pk accumulation order). d-inner keeps live state at x2/y2[32] v2f —
// no big arrays, no spill (r12 lesson).
// ---------------------------------------------------------------------------
__global__ __launch_bounds__(256)
void mlp_kernel(const float* __restrict__ xyz, const float* __restrict__ points,
                const float* __restrict__ new_xyz, const int* __restrict__ idx,
                const float* __restrict__ wt,
                float* __restrict__ feat)
{
    const float* Wt1 = wt;
    const float* Wt2 = wt + 512;
    const float* Wt3 = wt + 512 + 4096;
    const float* bi1 = wt + 512 + 4096 + 8192;
    const float* bi2 = bi1 + 64;
    const float* bi3 = bi2 + 64;

    const int tid  = threadIdx.x;
    const int wid  = tid >> 6;
    const int lane = tid & 63;
    const int q = blockIdx.x * 8 + wid * 2 + (lane >> 5);
    const int k = lane & 31;
    const int b = q >> 10;

    const int n = idx[(size_t)q * NSAMPLE + k];
    const float* xp = xyz    + ((size_t)b * NPTS + n) * 3;
    const float* pp = points + ((size_t)b * NPTS + n) * 3;
    const float* nx = new_xyz + (size_t)q * 3;

    const float in0 = __fsub_rn(xp[0], nx[0]);
    const float in1 = __fsub_rn(xp[1], nx[1]);
    const float in2 = __fsub_rn(xp[2], nx[2]);
    const float in3 = pp[0], in4 = pp[1], in5 = pp[2];

    // ---- Layer 1: 6 -> 64 ----
    v2f x2[32];
#pragma unroll
    for (int d = 0; d < 64; ++d) {
        const float4 wa = *(const float4*)(Wt1 + d * 8);
        const float4 wb = *(const float4*)(Wt1 + d * 8 + 4);
        float acc = bi1[d];
        acc = fmaf(in0, wa.x, acc);
        acc = fmaf(in1, wa.y, acc);
        acc = fmaf(in2, wa.z, acc);
        acc = fmaf(in3, wa.w, acc);
        acc = fmaf(in4, wb.x, acc);
        acc = fmaf(in5, wb.y, acc);
        float r = fmaxf(acc, 0.f);
        if (d & 1) x2[d >> 1].y = r; else x2[d >> 1].x = r;
    }

    // ---- Layer 2: 64 -> 64, pk-fma over c-pairs ----
    v2f y2[32];
#pragma unroll
    for (int d = 0; d < 64; ++d) {
        v2f a2; a2.x = 0.f; a2.y = 0.f;
        const float4* wr = (const float4*)(Wt2 + d * 64);
#pragma unroll
        for (int cc = 0; cc < 16; ++cc) {
            float4 w = wr[cc];
            v2f wlo; wlo.x = w.x; wlo.y = w.y;
            v2f whi; whi.x = w.z; whi.y = w.w;
            a2 += x2[2*cc]     * wlo;
            a2 += x2[2*cc + 1] * whi;
        }
        float r = fmaxf(bi2[d] + (a2.x + a2.y), 0.f);
        if (d & 1) y2[d >> 1].y = r; else y2[d >> 1].x = r;
    }

    // ---- Layer 3: 64 -> 128, pk-fma, fused max-pool + store ----
    float* fq = feat + (size_t)q * 128;
#pragma unroll
    for (int d = 0; d < 128; ++d) {
        v2f a2; a2.x = 0.f; a2.y = 0.f;
        const float4* wr = (const float4*)(Wt3 + d * 64);
#pragma unroll
        for (int cc = 0; cc < 16; ++cc) {
            float4 w = wr[cc];
            v2f wlo; wlo.x = w.x; wlo.y = w.y;
            v2f whi; whi.x = w.z; whi.y = w.w;
            a2 += y2[2*cc]     * wlo;
            a2 += y2[2*cc + 1] * whi;
        }
        float vv = fmaxf(bi3[d] + (a2.x + a2.y), 0.f);
#pragma unroll
        for (int off = 16; off >= 1; off >>= 1)
            vv = fmaxf(vv, __shfl_xor(vv, off));
        if (k == 0) fq[d] = vv;
    }
}

extern "C" void kernel_launch(void* const* d_in, const int* in_sizes, int n_in,
                              void* d_out, int out_size, void* d_ws, size_t ws_size,
                              hipStream_t stream)
{
    (void)in_sizes; (void)n_in; (void)out_size; (void)ws_size;

    const float* xyz    = (const float*)d_in[0];
    const float* points = (const float*)d_in[1];
    const float* W1 = (const float*)d_in[2];
    const float* g1 = (const float*)d_in[3];
    const float* b1 = (const float*)d_in[4];
    const float* m1 = (const float*)d_in[5];
    const float* v1 = (const float*)d_in[6];
    const float* W2 = (const float*)d_in[7];
    const float* g2 = (const float*)d_in[8];
    const float* b2 = (const float*)d_in[9];
    const float* m2 = (const float*)d_in[10];
    const float* v2 = (const float*)d_in[11];
    const float* W3 = (const float*)d_in[12];
    const float* g3 = (const float*)d_in[13];
    const float* b3 = (const float*)d_in[14];
    const float* m3 = (const float*)d_in[15];
    const float* v3 = (const float*)d_in[16];

    float* out_f    = (float*)d_out;
    float* new_xyz  = out_f;                                  // B*NPOINT*3
    float* feat     = out_f + (size_t)BATCH * NPOINT * 3;     // B*NPOINT*128
    int*   idx      = (int*)d_ws;                             // B*NPOINT*NSAMPLE ints
    float* wt       = (float*)((char*)d_ws +
                               (size_t)BATCH * NPOINT * NSAMPLE * sizeof(int));

    prep_kernel<<<1, 256, 0, stream>>>(W1, g1, b1, m1, v1,
                                       W2, g2, b2, m2, v2,
                                       W3, g3, b3, m3, v3, wt);
    fps_kernel <<<BATCH, 256, 0, stream>>>(xyz, new_xyz);
    ball_kernel<<<(BATCH * NPOINT) / 4, 256, 0, stream>>>(xyz, new_xyz, idx);
    mlp_kernel <<<(BATCH * NPOINT) / 8, 256, 0, stream>>>(xyz, points, new_xyz, idx,
                                                          wt, feat);
}

// Round 17
// 868.722 us; speedup vs baseline: 1.8838x; 1.0416x over previous
//
#include <hip/hip_runtime.h>

#define BATCH   16
#define NPTS    4096
#define NPOINT  1024
#define NSAMPLE 32

typedef float v2f __attribute__((ext_vector_type(2)));
typedef float v4f __attribute__((ext_vector_type(4)));
typedef const __attribute__((address_space(4))) float cs_float;
typedef const __attribute__((address_space(4))) v4f   cs_v4f;

// ---------------------------------------------------------------------------
// Kernel 1: farthest point sampling (parked at ~608us: six structural
// variants r5-r13 all land at 586-630 ns/iter -> serial barrier+LDS floor).
// 256 thr / 4 waves / 16 pts per thread in regs (VGPR=132, resident).
// ---------------------------------------------------------------------------
__global__ __attribute__((amdgpu_waves_per_eu(1, 1))) __launch_bounds__(256)
void fps_kernel(const float* __restrict__ xyz, float* __restrict__ new_xyz)
{
#pragma clang fp contract(off)
    const int b    = blockIdx.x;
    const int t    = threadIdx.x;
    const int lane = t & 63;
    const int wv   = t >> 6;                               // 0..3
    const float* xb = xyz + (size_t)b * NPTS * 3;

    __shared__ float sxyz4[NPTS * 4];                      // 64 KB, float4 stride
    __shared__ __align__(16) unsigned long long sCand[2][4];

    v2f px2[8], py2[8], pz2[8], dist2[8];
#pragma unroll
    for (int j = 0; j < 16; ++j) {
        const int n = j * 256 + t;
        float X = xb[n * 3 + 0];
        float Y = xb[n * 3 + 1];
        float Z = xb[n * 3 + 2];
        sxyz4[n * 4 + 0] = X; sxyz4[n * 4 + 1] = Y; sxyz4[n * 4 + 2] = Z;
        asm volatile("" : "+v"(X), "+v"(Y), "+v"(Z));
        const int p = j >> 1;
        if (j & 1) { px2[p].y = X; py2[p].y = Y; pz2[p].y = Z; dist2[p].y = 1e10f; }
        else       { px2[p].x = X; py2[p].x = Y; pz2[p].x = Z; dist2[p].x = 1e10f; }
    }
    __syncthreads();

    float cx = sxyz4[0], cy = sxyz4[1], cz = sxyz4[2];     // first centroid = pt 0
    float* out = new_xyz + (size_t)b * NPOINT * 3;

    for (int i = 0; i < NPOINT; ++i) {
        if (t == 0) { out[i*3+0] = cx; out[i*3+1] = cy; out[i*3+2] = cz; }

        v2f c2x; c2x.x = cx; c2x.y = cx;
        v2f c2y; c2y.x = cy; c2y.y = cy;
        v2f c2z; c2z.x = cz; c2z.y = cz;
#pragma unroll
        for (int p = 0; p < 8; ++p) {
            v2f dx = px2[p] - c2x;
            v2f dy = py2[p] - c2y;
            v2f dz = pz2[p] - c2z;
            v2f xx = dx * dx;
            v2f yy = dy * dy;
            v2f zz = dz * dz;
            v2f ss = (xx + yy) + zz;
            dist2[p].x = fminf(dist2[p].x, ss.x);
            dist2[p].y = fminf(dist2[p].y, ss.y);
        }

#define D(j) ((j) & 1 ? dist2[(j) >> 1].y : dist2[(j) >> 1].x)
        float mA = fmaxf(fmaxf(D(0),  D(1)),  D(2));
        float mB = fmaxf(fmaxf(D(3),  D(4)),  D(5));
        float mC = fmaxf(fmaxf(D(6),  D(7)),  D(8));
        float mD = fmaxf(fmaxf(D(9),  D(10)), D(11));
        float mE = fmaxf(fmaxf(D(12), D(13)), D(14));
        float mx = fmaxf(fmaxf(fmaxf(mA, mB), mC),
                         fmaxf(fmaxf(mD, mE), D(15)));
        int bj = 15;
#pragma unroll
        for (int j = 15; j >= 0; --j) bj = (D(j) == mx) ? j : bj;
#undef D
        const int bidx = bj * 256 + t;

        unsigned long long cand =
            ((unsigned long long)__float_as_uint(mx) << 32) |
            (unsigned long long)(unsigned int)~bidx;

#define DPP_RED(CTRL, RMASK)                                                   \
        {                                                                      \
            unsigned int oh = (unsigned int)__builtin_amdgcn_update_dpp(       \
                0, (int)(unsigned int)(cand >> 32), (CTRL), (RMASK), 0xF, true);\
            unsigned int ol = (unsigned int)__builtin_amdgcn_update_dpp(       \
                0, (int)(unsigned int)cand, (CTRL), (RMASK), 0xF, true);       \
            unsigned long long o =                                             \
                ((unsigned long long)oh << 32) | (unsigned long long)ol;       \
            if (o > cand) cand = o;                                            \
        }
        DPP_RED(0x121, 0xF)
        DPP_RED(0x122, 0xF)
        DPP_RED(0x124, 0xF)
        DPP_RED(0x128, 0xF)
        DPP_RED(0x142, 0xA)
        DPP_RED(0x143, 0xC)
#undef DPP_RED

        const int par = i & 1;
        if (lane == 63) sCand[par][wv] = cand;
        asm volatile("s_waitcnt lgkmcnt(0)\n\ts_barrier" ::: "memory");

        const ulonglong2* pc = (const ulonglong2*)&sCand[par][0];
        ulonglong2 r0 = pc[0], r1 = pc[1];
        const float4* sx4 = (const float4*)sxyz4;
        float4 f0 = sx4[~(unsigned int)r0.x];
        float4 f1 = sx4[~(unsigned int)r0.y];
        float4 f2 = sx4[~(unsigned int)r1.x];
        float4 f3 = sx4[~(unsigned int)r1.y];
        bool s01 = r0.y > r0.x;
        bool s23 = r1.y > r1.x;
        unsigned long long m01 = s01 ? r0.y : r0.x;
        unsigned long long m23 = s23 ? r1.y : r1.x;
        float4 g01; g01.x = s01 ? f1.x : f0.x; g01.y = s01 ? f1.y : f0.y; g01.z = s01 ? f1.z : f0.z;
        float4 g23; g23.x = s23 ? f3.x : f2.x; g23.y = s23 ? f3.y : f2.y; g23.z = s23 ? f3.z : f2.z;
        bool sF = m23 > m01;
        cx = sF ? g23.x : g01.x;
        cy = sF ? g23.y : g01.y;
        cz = sF ? g23.z : g01.z;
    }
}

// ---------------------------------------------------------------------------
// Kernel 2: ball query — software-pipelined chunk loads (r15). Identical
// values, identical _rn/fma op order — only load issue time moves; the
// validated discrete semantics are untouched.
// ---------------------------------------------------------------------------
__global__ __launch_bounds__(256)
void ball_kernel(const float* __restrict__ xyz, const float* __restrict__ new_xyz,
                 int* __restrict__ idx)
{
    const int q    = blockIdx.x * 4 + (threadIdx.x >> 6);
    const int lane = threadIdx.x & 63;
    const int b    = q >> 10;
    const float* xb = xyz + (size_t)b * NPTS * 3;
    const int NCH = NPTS / 64;

    const float s0 = new_xyz[q*3+0];
    const float s1 = new_xyz[q*3+1];
    const float s2 = new_xyz[q*3+2];
    const float ssum = __fadd_rn(__fadd_rn(__fmul_rn(s0,s0), __fmul_rn(s1,s1)),
                                 __fmul_rn(s2,s2));
    const float r2 = (float)(0.2 * 0.2);

    int* myidx = idx + (size_t)q * NSAMPLE;
    int found = 0;
    int first = -1;

    // prologue: load chunk 0
    float x = xb[lane*3+0], y = xb[lane*3+1], z = xb[lane*3+2];
    int c = 0;
    while (true) {
        // issue chunk c+1 loads early (hidden under processing of chunk c)
        float xn = 0.f, yn = 0.f, zn = 0.f;
        if (c + 1 < NCH) {
            const float* p = xb + ((size_t)(c + 1) * 64 + lane) * 3;
            xn = p[0]; yn = p[1]; zn = p[2];
        }

        // process chunk c — arithmetic EXACTLY as validated
        int n = c * 64 + lane;
        float nsum = __fadd_rn(__fadd_rn(__fmul_rn(x,x), __fmul_rn(y,y)), __fmul_rn(z,z));
        float dot  = __fmaf_rn(s2, z, __fmaf_rn(s1, y, __fmul_rn(s0, x)));
        float d2   = __fsub_rn(__fadd_rn(ssum, nsum), __fmul_rn(2.0f, dot));
        bool inb = !(d2 > r2);
        unsigned long long m = __ballot(inb);
        if (first < 0 && m != 0ull) first = c * 64 + (int)__builtin_ctzll(m);
        if (inb) {
            int rank = __popcll(m & ((1ull << lane) - 1ull));
            int slot = found + rank;
            if (slot < NSAMPLE) myidx[slot] = n;
        }
        found += __popcll(m);

        ++c;
        if (c >= NCH || found >= NSAMPLE) break;
        x = xn; y = yn; z = zn;
    }
    if (found > NSAMPLE) found = NSAMPLE;
    for (int slot = found + lane; slot < NSAMPLE; slot += 64) myidx[slot] = first;
}

// ---------------------------------------------------------------------------
// Kernel P: one-block prep — fold BN scale into TRANSPOSED weight copies in
// d_ws. Layout: Wt1[64][8] | Wt2[64][64] | Wt3[128][64] | bi1 | bi2 | bi3.
// ---------------------------------------------------------------------------
__global__ __launch_bounds__(256)
void prep_kernel(const float* __restrict__ W1, const float* __restrict__ g1,
                 const float* __restrict__ b1, const float* __restrict__ m1,
                 const float* __restrict__ v1,
                 const float* __restrict__ W2, const float* __restrict__ g2,
                 const float* __restrict__ b2, const float* __restrict__ m2,
                 const float* __restrict__ v2,
                 const float* __restrict__ W3, const float* __restrict__ g3,
                 const float* __restrict__ b3, const float* __restrict__ m3,
                 const float* __restrict__ v3,
                 float* __restrict__ wt)
{
    const int t = threadIdx.x;
    float* Wt1 = wt;                    // 512
    float* Wt2 = wt + 512;              // 4096
    float* Wt3 = wt + 512 + 4096;       // 8192
    float* bi1 = wt + 512 + 4096 + 8192;        // 64
    float* bi2 = bi1 + 64;                       // 64
    float* bi3 = bi2 + 64;                       // 128

    for (int e = t; e < 64 * 8; e += 256) {
        int d = e >> 3, c = e & 7;
        float sc = g1[d] / sqrtf(v1[d] + 1e-5f);
        Wt1[e] = (c < 6) ? W1[c * 64 + d] * sc : 0.f;
    }
    for (int e = t; e < 64 * 64; e += 256) {
        int d = e >> 6, c = e & 63;
        float sc = g2[d] / sqrtf(v2[d] + 1e-5f);
        Wt2[e] = W2[c * 64 + d] * sc;
    }
    for (int e = t; e < 128 * 64; e += 256) {
        int d = e >> 6, c = e & 63;
        float sc = g3[d] / sqrtf(v3[d] + 1e-5f);
        Wt3[e] = W3[c * 128 + d] * sc;
    }
    for (int d = t; d < 64; d += 256) {
        float s1v = g1[d] / sqrtf(v1[d] + 1e-5f);
        bi1[d] = b1[d] - m1[d] * s1v;
        float s2v = g2[d] / sqrtf(v2[d] + 1e-5f);
        bi2[d] = b2[d] - m2[d] * s2v;
    }
    for (int d = t; d < 128; d += 256) {
        float s3v = g3[d] / sqrtf(v3[d] + 1e-5f);
        bi3[d] = b3[d] - m3[d] * s3v;
    }
}

// ---------------------------------------------------------------------------
// Kernel 3: gather + 3-layer MLP + max-pool. Weights via CONSTANT address
// space through builtin ext_vector v4f (r16 fix: HIP float4 is a class and
// cannot copy from addrspace(4); builtin vectors can). Wave-uniform loads
// from addrspace(4) select to s_load_dwordx4 on the scalar/SMEM pipe.
// Max-pool via literal-ctrl DPP row_ror rounds + one xor-16 shuffle.
// Numerics identical to validated r13/r14.
// ---------------------------------------------------------------------------
__global__ __launch_bounds__(256)
void mlp_kernel(const float* __restrict__ xyz, const float* __restrict__ points,
                const float* __restrict__ new_xyz, const int* __restrict__ idx,
                const float* __restrict__ wt,
                float* __restrict__ feat)
{
    const cs_v4f*   Wc1 = (const cs_v4f*)(wt);                  // [64][2]
    const cs_v4f*   Wc2 = (const cs_v4f*)(wt + 512);            // [64][16]
    const cs_v4f*   Wc3 = (const cs_v4f*)(wt + 512 + 4096);     // [128][16]
    const cs_float* bi1 = (const cs_float*)(wt + 512 + 4096 + 8192);
    const cs_float* bi2 = bi1 + 64;
    const cs_float* bi3 = bi2 + 64;

    const int tid  = threadIdx.x;
    const int wid  = tid >> 6;
    const int lane = tid & 63;
    const int q = blockIdx.x * 8 + wid * 2 + (lane >> 5);
    const int k = lane & 31;
    const int b = q >> 10;

    const int n = idx[(size_t)q * NSAMPLE + k];
    const float* xp = xyz    + ((size_t)b * NPTS + n) * 3;
    const float* pp = points + ((size_t)b * NPTS + n) * 3;
    const float* nx = new_xyz + (size_t)q * 3;

    const float in0 = __fsub_rn(xp[0], nx[0]);
    const float in1 = __fsub_rn(xp[1], nx[1]);
    const float in2 = __fsub_rn(xp[2], nx[2]);
    const float in3 = pp[0], in4 = pp[1], in5 = pp[2];

    // ---- Layer 1: 6 -> 64 ----
    v2f x2[32];
#pragma unroll
    for (int d = 0; d < 64; ++d) {
        v4f wa = Wc1[d * 2 + 0];
        v4f wb = Wc1[d * 2 + 1];
        float acc = bi1[d];
        acc = fmaf(in0, wa.x, acc);
        acc = fmaf(in1, wa.y, acc);
        acc = fmaf(in2, wa.z, acc);
        acc = fmaf(in3, wa.w, acc);
        acc = fmaf(in4, wb.x, acc);
        acc = fmaf(in5, wb.y, acc);
        float r = fmaxf(acc, 0.f);
        if (d & 1) x2[d >> 1].y = r; else x2[d >> 1].x = r;
    }

    // ---- Layer 2: 64 -> 64, pk-fma over c-pairs ----
    v2f y2[32];
#pragma unroll
    for (int d = 0; d < 64; ++d) {
        v2f a2; a2.x = 0.f; a2.y = 0.f;
#pragma unroll
        for (int cc = 0; cc < 16; ++cc) {
            v4f w = Wc2[d * 16 + cc];
            v2f wlo; wlo.x = w.x; wlo.y = w.y;
            v2f whi; whi.x = w.z; whi.y = w.w;
            a2 += x2[2*cc]     * wlo;
            a2 += x2[2*cc + 1] * whi;
        }
        float r = fmaxf(bi2[d] + (a2.x + a2.y), 0.f);
        if (d & 1) y2[d >> 1].y = r; else y2[d >> 1].x = r;
    }

    // max over 16-lane row via DPP ring rotates (literal ctrl), then xor-16
#define POOL_MAX(vv)                                                           \
    {                                                                          \
        float o_;                                                              \
        o_ = __int_as_float(__builtin_amdgcn_update_dpp(                       \
            0, __float_as_int(vv), 0x121, 0xF, 0xF, true));                    \
        vv = fmaxf(vv, o_);                                                    \
        o_ = __int_as_float(__builtin_amdgcn_update_dpp(                       \
            0, __float_as_int(vv), 0x122, 0xF, 0xF, true));                    \
        vv = fmaxf(vv, o_);                                                    \
        o_ = __int_as_float(__builtin_amdgcn_update_dpp(                       \
            0, __float_as_int(vv), 0x124, 0xF, 0xF, true));                    \
        vv = fmaxf(vv, o_);                                                    \
        o_ = __int_as_float(__builtin_amdgcn_update_dpp(                       \
            0, __float_as_int(vv), 0x128, 0xF, 0xF, true));                    \
        vv = fmaxf(vv, o_);                                                    \
        vv = fmaxf(vv, __shfl_xor(vv, 16));                                    \
    }

    // ---- Layer 3: 64 -> 128, pk-fma, fused max-pool + store ----
    float* fq = feat + (size_t)q * 128;
#pragma unroll
    for (int d = 0; d < 128; ++d) {
        v2f a2; a2.x = 0.f; a2.y = 0.f;
#pragma unroll
        for (int cc = 0; cc < 16; ++cc) {
            v4f w = Wc3[d * 16 + cc];
            v2f wlo; wlo.x = w.x; wlo.y = w.y;
            v2f whi; whi.x = w.z; whi.y = w.w;
            a2 += y2[2*cc]     * wlo;
            a2 += y2[2*cc + 1] * whi;
        }
        float vv = fmaxf(bi3[d] + (a2.x + a2.y), 0.f);
        POOL_MAX(vv)
        if (k == 0) fq[d] = vv;
    }
#undef POOL_MAX
}

extern "C" void kernel_launch(void* const* d_in, const int* in_sizes, int n_in,
                              void* d_out, int out_size, void* d_ws, size_t ws_size,
                              hipStream_t stream)
{
    (void)in_sizes; (void)n_in; (void)out_size; (void)ws_size;

    const float* xyz    = (const float*)d_in[0];
    const float* points = (const float*)d_in[1];
    const float* W1 = (const float*)d_in[2];
    const float* g1 = (const float*)d_in[3];
    const float* b1 = (const float*)d_in[4];
    const float* m1 = (const float*)d_in[5];
    const float* v1 = (const float*)d_in[6];
    const float* W2 = (const float*)d_in[7];
    const float* g2 = (const float*)d_in[8];
    const float* b2 = (const float*)d_in[9];
    const float* m2 = (const float*)d_in[10];
    const float* v2 = (const float*)d_in[11];
    const float* W3 = (const float*)d_in[12];
    const float* g3 = (const float*)d_in[13];
    const float* b3 = (const float*)d_in[14];
    const float* m3 = (const float*)d_in[15];
    const float* v3 = (const float*)d_in[16];

    float* out_f    = (float*)d_out;
    float* new_xyz  = out_f;                                  // B*NPOINT*3
    float* feat     = out_f + (size_t)BATCH * NPOINT * 3;     // B*NPOINT*128
    int*   idx      = (int*)d_ws;                             // B*NPOINT*NSAMPLE ints
    float* wt       = (float*)((char*)d_ws +
                               (size_t)BATCH * NPOINT * NSAMPLE * sizeof(int));

    prep_kernel<<<1, 256, 0, stream>>>(W1, g1, b1, m1, v1,
                                       W2, g2, b2, m2, v2,
                                       W3, g3, b3, m3, v3, wt);
    fps_kernel <<<BATCH, 256, 0, stream>>>(xyz, new_xyz);
    ball_kernel<<<(BATCH * NPOINT) / 4, 256, 0, stream>>>(xyz, new_xyz, idx);
    mlp_kernel <<<(BATCH * NPOINT) / 8, 256, 0, stream>>>(xyz, points, new_xyz, idx,
                                                          wt, feat);
}